// Round 12
// baseline (206.542 us; speedup 1.0000x reference)
//
#include <hip/hip_runtime.h>

// N=524288, D=9, E=2, H=128, M=32, O=2, K=1.
// LAYOUT (confirmed R6): d_in fp32, d_out FP32 (N*2 outputs + 1 loss).
//
// R12: MFMA rewrite. R0-R11 evidence: every VALU+LDS/SMEM weight-delivery
// structure pins at 21-36% issue efficiency (~720-980 cyc per j per CU
// regardless of K/TLP/DS-traffic) — unfixable blind. MFMA moves the bulk
// (805M MAC) to the matrix pipe with weights resident in B-fragments.
// NUMERICS: gate = exact fp32 fmaf chain (gate flips were the 0.68 fails).
// MLP GEMM1 = one 16x16x32 bf16 MFMA per tile with 3-term split packing:
//   A slots 0-8:x_hi 9-17:x_lo 18-26:x_hi 27,28:1.0 ; B: w_hi,w_hi,w_lo,
//   b1_hi,b1_lo  ->  x.w + b1 with err ~5e-6 (x_lo.w_lo dropped).
// GEMM2 in fp32 VALU on the fp32 D-frags + exact w2'/bpp -> y err ~2e-6,
// sub-bf16-ulp; sigma(out)=0.19 => |y|<1.2 => absmax stays ~0.00195.
// Dense-both experts + per-token select by exact gate: NO partition/fixup.
#define NTOK 524288
#define TPB  256
#define NBLK (NTOK / TPB)   // 2048

typedef __attribute__((ext_vector_type(8))) short short8v;   // 8 bf16
typedef __attribute__((ext_vector_type(4))) float float4v;   // acc

union FragU { uint4 u; short8v s; };

__device__ __forceinline__ float bf2f(unsigned short u) {
    union { unsigned int i; float f; } v;
    v.i = ((unsigned int)u) << 16;
    return v.f;
}
__device__ __forceinline__ float ldq(const void* p, int i, bool f32) {
    if (f32) return ((const float*)p)[i];
    return bf2f(((const unsigned short*)p)[i]);
}
// truncation split: hi = top-16-bits of fp32 (exact bf16), lo = w - hi
__device__ __forceinline__ unsigned short btrunc(float w) {
    return (unsigned short)(__float_as_uint(w) >> 16);
}
__device__ __forceinline__ float hif(float w) {
    return __uint_as_float(__float_as_uint(w) & 0xFFFF0000u);
}

// ---------------------------------------------------------------------------
// Prep: dtype probe, zero counter, wgf (gate), bppf (b2@Wout+bout), w2f
// (W2@Wout fp32 [2][128][2]), wpackF (fp32 12-dw records, fallback only),
// wfragB: B-fragments for mfma_f32_16x16x32_bf16, [e][t][lane][4 u32].
// B lane l: col j = t*16 + (l&15), k-slots (l>>4)*8 + 0..7; slot s:
//   s<=8: w_hi[d=s]  s<=17: w_hi[s-9]  s<=26: w_lo[s-18]
//   s==27: b1_hi  s==28: b1_lo  else 0      (w = W1[e][d][j], b1[e][j])
// ---------------------------------------------------------------------------
__global__ void prep_kernel(const void* __restrict__ num_prop,
                            const void* __restrict__ wgate,
                            const void* __restrict__ W1,
                            const void* __restrict__ b1,
                            const void* __restrict__ W2,
                            const void* __restrict__ b2,
                            const void* __restrict__ Wout,
                            const void* __restrict__ bout,
                            unsigned int* __restrict__ cnt1,
                            int* __restrict__ flag,
                            float* __restrict__ bppf,
                            float* __restrict__ wgf,
                            float* __restrict__ w2f,
                            float* __restrict__ wpackF,
                            unsigned int* __restrict__ wfragB)
{
    __shared__ unsigned int bad;
    __shared__ int sflag;
    const int t = threadIdx.x;
    if (t == 0) { bad = 0u; *cnt1 = 0u; }
    __syncthreads();
    if (t < 72) {
        const unsigned short* u = (const unsigned short*)num_prop;
        int e = (u[t] >> 7) & 0xFF;
        if (e < 64 || e > 191) atomicOr(&bad, 1u);
    }
    __syncthreads();
    if (t == 0) { sflag = (int)bad; *flag = (int)bad; }
    __syncthreads();
    const bool f32 = (sflag != 0);

    if (t < 18) wgf[t] = ldq(wgate, t, f32);

    if (t < 4) {
        int e = t >> 1, o = t & 1;
        float acc = ldq(bout, o, f32);
        for (int m = 0; m < 32; ++m)
            acc += ldq(b2, e * 32 + m, f32) * ldq(Wout, m * 2 + o, f32);
        bppf[t] = acc;
    }

    {   // per (e,j): fold W2@Wout -> w2f; fp32 record -> wpackF (fallback)
        const int e = t >> 7, j = t & 127;
        float p0 = 0.f, p1 = 0.f;
        for (int m = 0; m < 32; ++m) {
            float w = ldq(W2, (e * 128 + j) * 32 + m, f32);
            p0 += w * ldq(Wout, m * 2 + 0, f32);
            p1 += w * ldq(Wout, m * 2 + 1, f32);
        }
        w2f[e * 256 + j * 2 + 0] = p0;
        w2f[e * 256 + j * 2 + 1] = p1;
        float* dst = wpackF + e * 1536 + j * 12;
        #pragma unroll
        for (int d = 0; d < 9; ++d)
            dst[d] = ldq(W1, (e * 9 + d) * 128 + j, f32);
        dst[9]  = ldq(b1, e * 128 + j, f32);
        dst[10] = p0;
        dst[11] = p1;
    }

    // wfragB: 1024 lane-entries, 4 per thread
    for (int q = 0; q < 4; ++q) {
        const int idx = t + q * 256;          // e*512 + t8*64 + l
        const int e  = idx >> 9;
        const int t8 = (idx >> 6) & 7;
        const int l  = idx & 63;
        const int j  = t8 * 16 + (l & 15);
        const int kg = l >> 4;
        const float bb = ldq(b1, e * 128 + j, f32);
        unsigned int u4[4];
        #pragma unroll
        for (int i = 0; i < 4; ++i) {
            unsigned short v[2];
            #pragma unroll
            for (int h = 0; h < 2; ++h) {
                const int s = kg * 8 + 2 * i + h;
                unsigned short r = 0;
                if (s <= 8) {
                    float w = ldq(W1, (e * 9 + s) * 128 + j, f32);
                    r = btrunc(w);
                } else if (s <= 17) {
                    float w = ldq(W1, (e * 9 + (s - 9)) * 128 + j, f32);
                    r = btrunc(w);
                } else if (s <= 26) {
                    float w = ldq(W1, (e * 9 + (s - 18)) * 128 + j, f32);
                    r = btrunc(w - hif(w));
                } else if (s == 27) {
                    r = btrunc(bb);
                } else if (s == 28) {
                    r = btrunc(bb - hif(bb));
                }
                v[h] = r;
            }
            u4[i] = (unsigned int)v[0] | ((unsigned int)v[1] << 16);
        }
        #pragma unroll
        for (int i = 0; i < 4; ++i) wfragB[idx * 4 + i] = u4[i];
    }
}

// ---------------------------------------------------------------------------
// Main: 256 tokens/block. Stage xs; exact-fp32 gate -> eflag; build xpack
// (A-fragments: split-packed x, [256][20 u32] padded rows); per wave 4
// 16-token groups: 1 A-read + 16 MFMA (8 h-tiles x 2 experts) + relu +
// fp32 GEMM2 glue with per-token expert select + shfl_xor(.,.,16) reduce.
// Output via LDS ob -> coalesced float2 stores.
// ---------------------------------------------------------------------------
__global__ __launch_bounds__(TPB)
void moe_main(const void* __restrict__ xg,
              const int* __restrict__ flag,
              const float* __restrict__ wgf,
              const float* __restrict__ bppf,
              const float* __restrict__ w2f,
              const float* __restrict__ wpackF,
              const unsigned int* __restrict__ wfragB,
              unsigned int* __restrict__ cnt1,
              float2* __restrict__ out)
{
    __shared__ __align__(16) float xs[TPB * 9];            // 9216 B
    __shared__ __align__(16) unsigned int xpk[TPB * 20];   // 20480 B (padded)
    __shared__ float2 ob[TPB];                             // 2048 B
    __shared__ unsigned char eflag[TPB];

    const int tid  = threadIdx.x;
    const int lane = tid & 63;
    const int wave = tid >> 6;
    const bool f32 = (*flag) != 0;
    const int tbase = blockIdx.x * TPB;

    if (f32) {
        const float4* xf4 = (const float4*)xg;
        float4* xsv = (float4*)xs;
        const int g4 = blockIdx.x * (TPB * 9 / 4);
        #pragma unroll
        for (int i = 0; i < 3; ++i) {
            const int idx = i * 256 + tid;
            if (idx < TPB * 9 / 4) xsv[idx] = xf4[g4 + idx];
        }
    } else {
        const unsigned short* xu = (const unsigned short*)xg;
        const int gbase = blockIdx.x * (TPB * 9);
        for (int i = tid; i < TPB * 9; i += TPB)
            xs[i] = bf2f(xu[gbase + i]);
    }
    __syncthreads();

    // --- exact fp32 gate (same fmaf chain as accepted kernel) ---
    float l0 = 0.f, l1 = 0.f;
    #pragma unroll
    for (int d = 0; d < 9; ++d) {
        const float xv = xs[tid * 9 + d];
        l0 = fmaf(xv, wgf[d * 2 + 0], l0);
        l1 = fmaf(xv, wgf[d * 2 + 1], l1);
    }
    const bool e1 = l1 > l0;              // tie -> expert 0 (stable top_k)
    eflag[tid] = e1 ? 1 : 0;
    unsigned long long bal = __ballot(e1);
    if (lane == 0) atomicAdd(cnt1, (unsigned int)__popcll(bal));

    if (!f32) {
        // bf16 fallback: dense-both via fp32 wpackF from global (never runs)
        float xr[9];
        #pragma unroll
        for (int d = 0; d < 9; ++d) xr[d] = xs[tid * 9 + d];
        float a00 = bppf[0], a01 = bppf[1], a10 = bppf[2], a11 = bppf[3];
        for (int j = 0; j < 128; ++j) {
            const float* r0 = wpackF + j * 12;
            const float* r1 = wpackF + 1536 + j * 12;
            float h0 = r0[9], h1 = r1[9];
            #pragma unroll
            for (int d = 0; d < 9; ++d) {
                h0 = fmaf(xr[d], r0[d], h0);
                h1 = fmaf(xr[d], r1[d], h1);
            }
            h0 = fmaxf(h0, 0.f); h1 = fmaxf(h1, 0.f);
            a00 = fmaf(h0, r0[10], a00); a01 = fmaf(h0, r0[11], a01);
            a10 = fmaf(h1, r1[10], a10); a11 = fmaf(h1, r1[11], a11);
        }
        out[tbase + tid] = make_float2(e1 ? a10 : a00, e1 ? a11 : a01);
        return;
    }

    // --- xpack: split-packed A row for token tid ---
    {
        unsigned short hv[9], lv[9];
        #pragma unroll
        for (int d = 0; d < 9; ++d) {
            const float xv = xs[tid * 9 + d];
            hv[d] = btrunc(xv);
            lv[d] = btrunc(xv - hif(xv));
        }
        const unsigned int ONE = 0x3F80u;   // bf16 1.0
        #define PK(a,b) ((unsigned int)(a) | ((unsigned int)(b) << 16))
        uint4* xp = (uint4*)&xpk[tid * 20];
        xp[0] = make_uint4(PK(hv[0],hv[1]), PK(hv[2],hv[3]),
                           PK(hv[4],hv[5]), PK(hv[6],hv[7]));
        xp[1] = make_uint4(PK(hv[8],lv[0]), PK(lv[1],lv[2]),
                           PK(lv[3],lv[4]), PK(lv[5],lv[6]));
        xp[2] = make_uint4(PK(lv[7],lv[8]), PK(hv[0],hv[1]),
                           PK(hv[2],hv[3]), PK(hv[4],hv[5]));
        xp[3] = make_uint4(PK(hv[6],hv[7]), PK(hv[8],ONE),
                           PK(ONE,0u), 0u);
        #undef PK
    }
    __syncthreads();

    // --- one-time per-wave preloads: B-frags (16) + w2' (16 float2) ---
    FragU bw[16];                       // [e*8 + t]
    #pragma unroll
    for (int et = 0; et < 16; ++et)
        bw[et].u = ((const uint4*)wfragB)[et * 64 + lane];
    float2 w2v[16];
    #pragma unroll
    for (int et = 0; et < 16; ++et) {
        const int e = et >> 3, t8 = et & 7;
        w2v[et] = ((const float2*)w2f)[e * 128 + t8 * 16 + (lane & 15)];
    }
    const float bp0 = bppf[0], bp1 = bppf[1], bp2 = bppf[2], bp3 = bppf[3];
    const float4v zero4 = {0.f, 0.f, 0.f, 0.f};

    // --- 4 groups of 16 tokens per wave ---
    #pragma unroll
    for (int r = 0; r < 4; ++r) {
        const int tb16 = wave * 64 + r * 16;
        FragU av;
        av.u = *(const uint4*)&xpk[(tb16 + (lane & 15)) * 20 + ((lane >> 4) << 2)];
        const unsigned int efw =
            *(const unsigned int*)&eflag[tb16 + ((lane >> 4) << 2)];

        float4v d0[8], d1[8];
        #pragma unroll
        for (int t8 = 0; t8 < 8; ++t8)
            d0[t8] = __builtin_amdgcn_mfma_f32_16x16x32_bf16(av.s, bw[t8].s, zero4, 0, 0, 0);
        #pragma unroll
        for (int t8 = 0; t8 < 8; ++t8)
            d1[t8] = __builtin_amdgcn_mfma_f32_16x16x32_bf16(av.s, bw[8 + t8].s, zero4, 0, 0, 0);

        float yx0 = 0.f, yx1 = 0.f, yx2 = 0.f, yx3 = 0.f;
        float yy0 = 0.f, yy1 = 0.f, yy2 = 0.f, yy3 = 0.f;
        const bool b0 = (efw >> 0)  & 1;
        const bool b1b = (efw >> 8)  & 1;
        const bool b2b = (efw >> 16) & 1;
        const bool b3b = (efw >> 24) & 1;
        #pragma unroll
        for (int t8 = 0; t8 < 8; ++t8) {
            const float4v v0 = d0[t8], v1 = d1[t8];
            const float2 wa = w2v[t8], wb = w2v[8 + t8];
            {   // token row 0
                float h = b0 ? fmaxf(v1[0], 0.f) : fmaxf(v0[0], 0.f);
                yx0 = fmaf(h, b0 ? wb.x : wa.x, yx0);
                yy0 = fmaf(h, b0 ? wb.y : wa.y, yy0);
            }
            {   // row 1
                float h = b1b ? fmaxf(v1[1], 0.f) : fmaxf(v0[1], 0.f);
                yx1 = fmaf(h, b1b ? wb.x : wa.x, yx1);
                yy1 = fmaf(h, b1b ? wb.y : wa.y, yy1);
            }
            {   // row 2
                float h = b2b ? fmaxf(v1[2], 0.f) : fmaxf(v0[2], 0.f);
                yx2 = fmaf(h, b2b ? wb.x : wa.x, yx2);
                yy2 = fmaf(h, b2b ? wb.y : wa.y, yy2);
            }
            {   // row 3
                float h = b3b ? fmaxf(v1[3], 0.f) : fmaxf(v0[3], 0.f);
                yx3 = fmaf(h, b3b ? wb.x : wa.x, yx3);
                yy3 = fmaf(h, b3b ? wb.y : wa.y, yy3);
            }
        }
        // reduce over the 16 hidden-lanes (butterfly, width 16)
        #pragma unroll
        for (int m = 1; m < 16; m <<= 1) {
            yx0 += __shfl_xor(yx0, m, 16); yy0 += __shfl_xor(yy0, m, 16);
            yx1 += __shfl_xor(yx1, m, 16); yy1 += __shfl_xor(yy1, m, 16);
            yx2 += __shfl_xor(yx2, m, 16); yy2 += __shfl_xor(yy2, m, 16);
            yx3 += __shfl_xor(yx3, m, 16); yy3 += __shfl_xor(yy3, m, 16);
        }
        if ((lane & 15) == 0) {
            const int tk = tb16 + ((lane >> 4) << 2);
            ob[tk + 0] = make_float2(yx0 + (b0  ? bp2 : bp0), yy0 + (b0  ? bp3 : bp1));
            ob[tk + 1] = make_float2(yx1 + (b1b ? bp2 : bp0), yy1 + (b1b ? bp3 : bp1));
            ob[tk + 2] = make_float2(yx2 + (b2b ? bp2 : bp0), yy2 + (b2b ? bp3 : bp1));
            ob[tk + 3] = make_float2(yx3 + (b3b ? bp2 : bp0), yy3 + (b3b ? bp3 : bp1));
        }
    }
    __syncthreads();
    out[tbase + tid] = ob[tid];
}

// Loss: counts-based cv^2 (ddof=1), as validated.
__global__ void finalize_kernel(const unsigned int* __restrict__ cnt1,
                                float* __restrict__ loss_out)
{
    double c1 = (double)(*cnt1);
    double c0 = (double)NTOK - c1;
    double diff = c0 - c1;
    double mean = (double)NTOK * 0.5;
    double var  = 0.5 * diff * diff;
    double cv2  = var / (mean * mean + 1e-10);
    *loss_out = (float)(0.02 * cv2);
}

extern "C" void kernel_launch(void* const* d_in, const int* in_sizes, int n_in,
                              void* d_out, int out_size, void* d_ws, size_t ws_size,
                              hipStream_t stream) {
    const void* num_prop = d_in[0]; // [N,9] fp32
    const void* w_gate   = d_in[2]; // [9,2]
    const void* W1       = d_in[3]; // [2,9,128]
    const void* b1       = d_in[4]; // [2,128]
    const void* W2       = d_in[5]; // [2,128,32]
    const void* b2       = d_in[6]; // [2,32]
    const void* Wout     = d_in[7]; // [32,2]
    const void* bout     = d_in[8]; // [2]

    char* ws = (char*)d_ws;
    unsigned int* cnt1   = (unsigned int*)ws;        // @0
    int* flag            = (int*)(ws + 8);           // @8
    float* bppf          = (float*)(ws + 16);        // 4 f
    float* wgf           = (float*)(ws + 64);        // 18 f
    float* w2f           = (float*)(ws + 192);       // 512 f  -> ends 2240
    float* wpackF        = (float*)(ws + 2304);      // 3072 f -> ends 14592
    unsigned int* wfragB = (unsigned int*)(ws + 14592); // 4096 u32 -> ends 30976

    float*  outf = (float*)d_out;                    // FP32: N*2 + loss
    float2* out2 = (float2*)d_out;

    hipLaunchKernelGGL(prep_kernel, dim3(1), dim3(256), 0, stream,
                       num_prop, w_gate, W1, b1, W2, b2, Wout, bout,
                       cnt1, flag, bppf, wgf, w2f, wpackF, wfragB);
    hipLaunchKernelGGL(moe_main, dim3(NBLK), dim3(TPB), 0, stream,
                       num_prop, flag, wgf, bppf, w2f, wpackF, wfragB,
                       cnt1, out2);
    hipLaunchKernelGGL(finalize_kernel, dim3(1), dim3(1), 0, stream,
                       cnt1, outf + (size_t)NTOK * 2);
}